// Round 6
// baseline (89.343 us; speedup 1.0000x reference)
//
#include <hip/hip_runtime.h>
#include <hip/hip_bf16.h>

// KAN conv: 8x KANLinear(9->1) over 3x3 patches, 256 images of 64x64.
// R5 = R4 resubmit (acquisition timeout, never benched).
// fp16 feature planes (LDS 23.2->11.9 KB) + launch_bounds(256,8)
// -> 32 waves/CU (vs 20). Grid 2048 = one full-occupancy round.
// Phase 1: per-pixel features (silu + 8 cubic B-spline bases, closed-form
//          uniform-knot segments) -> LDS fp16 SoA planes feat[9][10][66].
// Phase 2: 2 consecutive output cols x 8 convs per thread; folded weights
//          in d_ws, dense 24-float chunks -> batched s_loads.

#define N_CONVS 8
#define HH 64
#define WW 64
#define HO 62
#define WO 62
#define BAND 8
#define LROWS 10                // BAND + 2
#define PW 66                   // plane row pitch (halfs); 132B row -> 2-way banks
#define PLANE (LROWS * PW)      // 660 halfs per plane

typedef _Float16 half2v __attribute__((ext_vector_type(2)));

// wf layout: [ky*9+j][32] floats; slot r (r<24): n=r/3, kx=r%3; 24..31 pad.
// j==0 -> base_weight (pairs with silu plane), j>=1 -> sc*sw[...][j-1].
__global__ __launch_bounds__(864) void kan_prep(const float* __restrict__ bw,
                                                const float* __restrict__ sw,
                                                const float* __restrict__ sc,
                                                float* __restrict__ wf) {
    const int t = threadIdx.x;          // 0..863
    const int chunk = t >> 5;           // ky*9 + j
    const int r = t & 31;
    const int ky = chunk / 9, j = chunk % 9;
    float v = 0.0f;
    if (r < 24) {
        const int n = r / 3, kx = r % 3;
        const int i = ky * 3 + kx;
        v = (j == 0) ? bw[n * 9 + i]
                     : sw[(n * 9 + i) * 8 + (j - 1)] * sc[n * 9 + i];
    }
    wf[t] = v;
}

__global__ __launch_bounds__(256, 8) void kan_main(
    const float* __restrict__ x,     // [256,64,64]
    const float* __restrict__ grid,  // 12 uniform knots (first row)
    const float* __restrict__ wf,    // folded weights (864 floats)
    float* __restrict__ out)         // [256*8,62,62]
{
    __shared__ _Float16 feat[9 * PLANE];   // 11.9 KB

    const int blk  = blockIdx.x;
    const int band = blk & 7;
    const int img  = blk >> 3;
    const int r0   = band * BAND;
    const int nr   = (HO - r0) < BAND  ? (HO - r0) : BAND;    // 8 (band7: 6)
    const int nin  = (HH - r0) < LROWS ? (HH - r0) : LROWS;   // 10 (band7: 8)

    const float g0   = grid[0];
    const float invh = __builtin_amdgcn_rcpf(grid[1] - grid[0]);

    // ---- Phase 1: per-pixel features into fp16 SoA planes ----
    const float* xb = x + (size_t)img * (HH * WW) + (size_t)r0 * WW;
    for (int p = threadIdx.x; p < nin * WW; p += 256) {
        const int r = p >> 6, c = p & 63;
        const float xv = xb[p];

        _Float16* fp = &feat[r * PW + c];
        fp[0] = (_Float16)(xv * __builtin_amdgcn_rcpf(1.0f + __expf(-xv)));
#pragma unroll
        for (int j = 1; j < 9; j++) fp[j * PLANE] = (_Float16)0.0f;

        const float u0 = (xv - g0) * invh;
        const int   m  = (int)floorf(u0);
        if (m >= 0 && m <= 10) {
            const float u  = u0 - (float)m;
            const float um = 1.0f - u;
            const float u2 = u * u, u3 = u2 * u;
            const float N0 = um * um * um * (1.0f / 6.0f);
            const float N1 = (3.0f * u3 - 6.0f * u2 + 4.0f) * (1.0f / 6.0f);
            const float N2 = (-3.0f * u3 + 3.0f * u2 + 3.0f * u + 1.0f) * (1.0f / 6.0f);
            const float N3 = u3 * (1.0f / 6.0f);
            const float Nv[4] = {N0, N1, N2, N3};
            // B_j nonzero for j = m-3..m (within 0..7); B_{m-3+s} = Nv[s]
#pragma unroll
            for (int s = 0; s < 4; s++) {
                const int j = m - 3 + s;
                if (j >= 0 && j <= 7) fp[(j + 1) * PLANE] = (_Float16)Nv[s];
            }
        }
    }
    __syncthreads();

    // ---- Phase 2: 2 consecutive output cols x 8 convs per thread ----
    const int row = threadIdx.x >> 5;          // 0..7
    const int xs  = (threadIdx.x & 31) << 1;   // 0,2,..,62

    float acc[N_CONVS][2];
#pragma unroll
    for (int n = 0; n < N_CONVS; n++) { acc[n][0] = 0.0f; acc[n][1] = 0.0f; }

#pragma unroll 1
    for (int ky = 0; ky < 3; ky++) {
#pragma unroll
        for (int j = 0; j < 9; j++) {
            const _Float16* pl = &feat[j * PLANE + (row + ky) * PW + xs];
            const half2v a = *(const half2v*)pl;        // ds_read_b32
            const half2v b = *(const half2v*)(pl + 2);  // ds_read_b32
            const float fv[4] = {(float)a.x, (float)a.y, (float)b.x, (float)b.y};
            const float* gg = wf + ((ky * 9 + j) << 5); // uniform -> s_load
#pragma unroll
            for (int n = 0; n < N_CONVS; n++) {
#pragma unroll
                for (int kx = 0; kx < 3; kx++) {
                    const float w = gg[n * 3 + kx];
                    acc[n][0] = fmaf(w, fv[kx],     acc[n][0]);
                    acc[n][1] = fmaf(w, fv[kx + 1], acc[n][1]);
                }
            }
        }
    }

    if (row < nr && xs < WO) {
        const int oy = r0 + row;
        float* ob = out + (size_t)img * N_CONVS * (HO * WO) + oy * WO + xs;
#pragma unroll
        for (int n = 0; n < N_CONVS; n++)
            *(float2*)(ob + n * (HO * WO)) = make_float2(acc[n][0], acc[n][1]);
    }
}

extern "C" void kernel_launch(void* const* d_in, const int* in_sizes, int n_in,
                              void* d_out, int out_size, void* d_ws, size_t ws_size,
                              hipStream_t stream) {
    const float* x    = (const float*)d_in[0];
    const float* bw   = (const float*)d_in[1];
    const float* sw   = (const float*)d_in[2];
    const float* sc   = (const float*)d_in[3];
    const float* grid = (const float*)d_in[4];
    float* out = (float*)d_out;
    float* wf  = (float*)d_ws;

    kan_prep<<<1, 864, 0, stream>>>(bw, sw, sc, wf);
    kan_main<<<256 * 8, 256, 0, stream>>>(x, grid, wf, out);
}